// Round 1
// baseline (688.926 us; speedup 1.0000x reference)
//
#include <hip/hip_runtime.h>

#define CIN  128
#define COUT 128
#define SDIM 512
#define IMG  256

typedef _Float16 f16x8 __attribute__((ext_vector_type(8)));
typedef float    f32x4 __attribute__((ext_vector_type(4)));

// ---------------------------------------------------------------------------
// ws layout:
//   [0, 4KB)            style[b][cin]  f32   (8*128)
//   [4KB, +2359296)     wfrag          f16   A-fragments: [b][ks=36][mt=8][lane=64][e=8]
//   [+.., +134217728)   x_t            f16   [b][cc=4][y][x][ci=32]  (ci-contiguous)
// total ~130.3 MiB
// ---------------------------------------------------------------------------

// kernel 1: style[b][cin] = sum_s w[b][s]*style_W[cin][s] + style_b[cin]
__global__ void k_style(const float* __restrict__ w, const float* __restrict__ sW,
                        const float* __restrict__ sb, float* __restrict__ style) {
  int b = blockIdx.x >> 3, cg = blockIdx.x & 7;
  int ci = threadIdx.x >> 4, s0 = threadIdx.x & 15;
  int cin = cg * 16 + ci;
  const float* wr  = w + b * SDIM;
  const float* swr = sW + (size_t)cin * SDIM;
  float acc = 0.f;
  for (int s = s0; s < SDIM; s += 16) acc += wr[s] * swr[s];
#pragma unroll
  for (int m = 1; m < 16; m <<= 1) acc += __shfl_xor(acc, m, 64);
  if (s0 == 0) style[b * CIN + cin] = acc + sb[cin];
}

// kernel 2: modulate+demodulate, write f16 A-fragments.
// K order: ks = cc*9 + tap (cc = cin>>5), within-step slot: kq=(cin&31)>>3, j=cin&7
// A-frag lane = (cout&15) | (kq<<4), elem = j, mtile = cout>>4.
__global__ void k_wfrag(const float* __restrict__ weight, const float* __restrict__ style,
                        _Float16* __restrict__ wfrag) {
  int cout = blockIdx.x, b = blockIdx.y;
  int t = threadIdx.x;                      // 64 threads = 1 wave
  const float* wrow = weight + (size_t)cout * 1152;
  const float* srow = style + b * CIN;
  float vals[18];
  float ssum = 0.f;
#pragma unroll
  for (int i = 0; i < 18; ++i) {
    int e = t + i * 64;                     // < 1152
    int cin = e / 9;
    float v = wrow[e] * srow[cin];
    vals[i] = v;
    ssum += v * v;
  }
#pragma unroll
  for (int m = 1; m < 64; m <<= 1) ssum += __shfl_xor(ssum, m, 64);
  float d = rsqrtf(ssum + 1e-8f);
  int mt = cout >> 4, ml = cout & 15;
#pragma unroll
  for (int i = 0; i < 18; ++i) {
    int e = t + i * 64;
    int cin = e / 9, tap = e % 9;
    int cc = cin >> 5, ci = cin & 31;
    int ks = cc * 9 + tap;
    int kq = ci >> 3, j = ci & 7;
    int fl = ml | (kq << 4);
    int idx = (((b * 36 + ks) * 8 + mt) * 64 + fl) * 8 + j;
    wfrag[idx] = (_Float16)(vals[i] * d);
  }
}

// kernel 3: x (f32, [b][cin][y][x]) -> x_t (f16, [b][cc][y][x][ci32])
__global__ void k_xt(const float* __restrict__ x, _Float16* __restrict__ xt) {
  int y = blockIdx.x, cc = blockIdx.y, b = blockIdx.z;
  int q = threadIdx.x & 3, xl = threadIdx.x >> 2;   // 64 x-values per pass
  const float* xb = x + ((size_t)b * CIN + cc * 32) * (IMG * IMG) + (size_t)y * IMG;
  f16x8* orow = (f16x8*)(xt + ((size_t)((b * 4 + cc) * IMG + y)) * IMG * 32);
#pragma unroll
  for (int xi = 0; xi < 4; ++xi) {
    int xx = xi * 64 + xl;
    f16x8 v;
#pragma unroll
    for (int j = 0; j < 8; ++j)
      v[j] = (_Float16)xb[(size_t)(q * 8 + j) * (IMG * IMG) + xx];
    orow[xx * 4 + q] = v;                           // 16B unit = 8 consecutive ci
  }
}

// kernel 4: implicit-GEMM conv. Block: 256 thr (4 waves, 2M x 2N).
// Output tile: 128 cout x (64 cols x 4 rows). LDS X tile: 6 rows x 66 cols x 32 ci,
// stored as 16B units with XOR slot swizzle; double-buffered over 4 cin-chunks.
__global__ __launch_bounds__(256, 2) void k_conv(
    const _Float16* __restrict__ wfrag, const int4* __restrict__ xt,
    const float* __restrict__ bias, float* __restrict__ out) {
  int x0 = blockIdx.x * 64, y0 = blockIdx.y * 4, b = blockIdx.z;
  int tid = threadIdx.x;
  int lane = tid & 63, wv = tid >> 6;
  int wm = wv >> 1, wn = wv & 1;               // wave tile: 64 cout x (64x2 px)
  int l15 = lane & 15, kq = lane >> 4;

  __shared__ int4 xls[2][1584];                // 2 x 6*264 units = 50688 B

  f32x4 acc[4][8];
#pragma unroll
  for (int m = 0; m < 4; ++m)
#pragma unroll
    for (int t = 0; t < 8; ++t)
      acc[m][t] = (f32x4){0.f, 0.f, 0.f, 0.f};

  for (int cc = 0; cc < 4; ++cc) {
    // ---- stage chunk cc: rows y0-1..y0+4, cols x0-1..x0+64, 32 ci, zero-pad ----
    {
      const int4* src = xt + ((size_t)(b * 4 + cc)) * IMG * IMG * 4;
      for (int i = tid; i < 1584; i += 256) {
        int row = i / 264, rem = i % 264;
        int col = rem >> 2, q = rem & 3;
        int gy = y0 - 1 + row, gx = x0 - 1 + col;
        int4 v = {0, 0, 0, 0};
        if ((unsigned)gy < IMG && (unsigned)gx < IMG)
          v = src[((size_t)gy * IMG + gx) * 4 + q];
        int s8 = (((col & 1) << 2) | q) ^ ((col >> 1) & 7);
        xls[cc & 1][row * 264 + (col >> 1) * 8 + s8] = v;
      }
    }
    __syncthreads();

    const _Float16* ab = wfrag + ((size_t)(b * 36 + cc * 9)) * 4096;  // 4096 halves per ks
#pragma unroll
    for (int tap = 0; tap < 9; ++tap) {
      int dy = tap / 3, dx = tap % 3;
      f16x8 af[4];
#pragma unroll
      for (int m = 0; m < 4; ++m)
        af[m] = *(const f16x8*)(ab + tap * 4096 + ((wm * 4 + m) * 64 + lane) * 8);
#pragma unroll
      for (int t = 0; t < 8; ++t) {
        int row = wn * 2 + (t >> 2) + dy;          // 0..5
        int col = (t & 3) * 16 + l15 + dx;         // 0..65
        int s8 = (((col & 1) << 2) | kq) ^ ((col >> 1) & 7);
        f16x8 bf = *(const f16x8*)&xls[cc & 1][row * 264 + (col >> 1) * 8 + s8];
#pragma unroll
        for (int m = 0; m < 4; ++m)
          acc[m][t] = __builtin_amdgcn_mfma_f32_16x16x32_f16(af[m], bf, acc[m][t], 0, 0, 0);
      }
    }
    __syncthreads();
  }

  // ---- epilogue: D[row=(lane>>4)*4+r][col=lane&15], +bias, f32 out ----
#pragma unroll
  for (int m = 0; m < 4; ++m) {
    int coutb = wm * 64 + m * 16 + kq * 4;
#pragma unroll
    for (int t = 0; t < 8; ++t) {
      int oy = y0 + wn * 2 + (t >> 2);
      int ox = x0 + (t & 3) * 16 + l15;
      float* op = out + ((size_t)(b * COUT + coutb) * IMG + oy) * IMG + ox;
#pragma unroll
      for (int r = 0; r < 4; ++r)
        op[(size_t)r * IMG * IMG] = acc[m][t][r] + bias[coutb + r];
    }
  }
}

extern "C" void kernel_launch(void* const* d_in, const int* in_sizes, int n_in,
                              void* d_out, int out_size, void* d_ws, size_t ws_size,
                              hipStream_t stream) {
  const float* x    = (const float*)d_in[0];
  const float* w    = (const float*)d_in[1];
  const float* wt   = (const float*)d_in[2];
  const float* sW   = (const float*)d_in[3];
  const float* sb   = (const float*)d_in[4];
  const float* bias = (const float*)d_in[5];
  float* out = (float*)d_out;

  float*    style = (float*)d_ws;
  _Float16* wfrag = (_Float16*)((char*)d_ws + 4096);
  _Float16* xtw   = (_Float16*)((char*)d_ws + 4096 + 2359296);

  k_style<<<64, 256, 0, stream>>>(w, sW, sb, style);
  k_wfrag<<<dim3(COUT, 8), 64, 0, stream>>>(wt, style, wfrag);
  k_xt<<<dim3(IMG, 4, 8), 256, 0, stream>>>(x, xtw);
  k_conv<<<dim3(4, 64, 8), 256, 0, stream>>>(wfrag, (const int4*)xtw, bias, out);
}